// Round 1
// baseline (2558.529 us; speedup 1.0000x reference)
//
#include <hip/hip_runtime.h>
#include <hip/hip_bf16.h>
#include <math.h>
#include <stdint.h>

// ---------------- CSR build ----------------
__global__ void fill_zero_i32(int* __restrict__ p, int n){
  int i = blockIdx.x*blockDim.x + threadIdx.x;
  if(i < n) p[i] = 0;
}

__global__ void count_dst_k(const int* __restrict__ dst, int E, int* __restrict__ cnt){
  int i = blockIdx.x*blockDim.x + threadIdx.x;
  if(i < E) atomicAdd(&cnt[dst[i]], 1);
}

__global__ __launch_bounds__(1024) void scan_excl_k(const int* __restrict__ cnt,
    int* __restrict__ ofs, int* __restrict__ cursor, int n){
  __shared__ int tmp[1024];
  __shared__ int carry_s;
  int tid = threadIdx.x;
  if(tid == 0) carry_s = 0;
  __syncthreads();
  for(int base = 0; base < n; base += 1024){
    int i = base + tid;
    int v = (i < n) ? cnt[i] : 0;
    tmp[tid] = v;
    __syncthreads();
    for(int off = 1; off < 1024; off <<= 1){
      int t = (tid >= off) ? tmp[tid-off] : 0;
      __syncthreads();
      tmp[tid] += t;
      __syncthreads();
    }
    if(i < n){ int e = tmp[tid] - v + carry_s; ofs[i] = e; cursor[i] = e; }
    __syncthreads();
    if(tid == 0) carry_s += tmp[1023];
    __syncthreads();
  }
  if(tid == 0) ofs[n] = carry_s;
}

__global__ void scatter_k(const int* __restrict__ src, const int* __restrict__ dst,
    int E, int* __restrict__ cursor, int* __restrict__ colv){
  int i = blockIdx.x*blockDim.x + threadIdx.x;
  if(i < E){ int p = atomicAdd(&cursor[dst[i]], 1); colv[p] = src[i]; }
}

// ---------------- attention-weight fold: Wf[k,h] = sum_d W[k, h*D+d]*a[h,d] ----------------
__global__ void fold_k(const float* __restrict__ W, const float* __restrict__ a,
    float* __restrict__ Wf, int K, int D){
  int i = blockIdx.x*blockDim.x + threadIdx.x;
  if(i >= K*4) return;
  int k = i >> 2, h = i & 3;
  const float* wr = W + (size_t)k*4*D + (size_t)h*D;
  const float* ar = a + (size_t)h*D;
  float s = 0.f;
  for(int d = 0; d < D; d++) s += wr[d]*ar[d];
  Wf[k*4 + h] = s;
}

// ---------------- out[m,0:4] = A[m,:] @ Wf[:,0:4]  (one wave per row) ----------------
__global__ __launch_bounds__(256) void gemv4_k(const float* __restrict__ A,
    const float* __restrict__ Wf, float* __restrict__ outv, int M, int K, int lda){
  int wid = (blockIdx.x*blockDim.x + threadIdx.x) >> 6;
  int lane = threadIdx.x & 63;
  if(wid >= M) return;
  const float* arow = A + (size_t)wid*lda;
  float a0=0.f, a1=0.f, a2=0.f, a3=0.f;
  for(int k = lane; k < K; k += 64){
    float av = arow[k];
    float4 w = *(const float4*)(Wf + k*4);
    a0 += av*w.x; a1 += av*w.y; a2 += av*w.z; a3 += av*w.w;
  }
  #pragma unroll
  for(int off = 32; off; off >>= 1){
    a0 += __shfl_down(a0, off); a1 += __shfl_down(a1, off);
    a2 += __shfl_down(a2, off); a3 += __shfl_down(a3, off);
  }
  if(lane == 0){
    float4 r; r.x=a0; r.y=a1; r.z=a2; r.w=a3;
    *(float4*)(outv + (size_t)wid*4) = r;
  }
}

// ---------------- tiled fp32 GEMM: C[M,N] = A[M,K] @ B[K,N] (+bias) ----------------
template<int TM, int TN>
__global__ __launch_bounds__(256) void gemm_k(const float* __restrict__ A,
    const float* __restrict__ B, const float* __restrict__ bias, float* __restrict__ C,
    int M, int N, int K, int lda, int ldb, int ldc){
  const int CM = TM/64, CN = TN/64;
  __shared__ float As[16][TM+4];
  __shared__ float Bs[16][TN+4];
  int tid = threadIdx.x;
  int tx = tid & 15, ty = tid >> 4;
  int rowbase = blockIdx.x*TM, colbase = blockIdx.y*TN;
  float acc[CM*4][CN*4];
  #pragma unroll
  for(int i = 0; i < CM*4; i++)
    #pragma unroll
    for(int j = 0; j < CN*4; j++) acc[i][j] = 0.f;

  for(int k0 = 0; k0 < K; k0 += 16){
    for(int idx = tid; idx < TM*16; idx += 256){
      int r = idx >> 4, kk = idx & 15;
      int row = rowbase + r;
      As[kk][r] = (row < M) ? A[(size_t)row*lda + (k0+kk)] : 0.f;
    }
    for(int idx = tid; idx < 16*TN; idx += 256){
      int kk = idx / TN, c = idx % TN;
      int colg = colbase + c;
      Bs[kk][c] = (colg < N) ? B[(size_t)(k0+kk)*ldb + colg] : 0.f;
    }
    __syncthreads();
    #pragma unroll
    for(int kk = 0; kk < 16; kk++){
      float av[CM*4], bv[CN*4];
      #pragma unroll
      for(int c = 0; c < CM; c++){
        float4 t = *(const float4*)&As[kk][c*64 + ty*4];
        av[c*4+0]=t.x; av[c*4+1]=t.y; av[c*4+2]=t.z; av[c*4+3]=t.w;
      }
      #pragma unroll
      for(int c = 0; c < CN; c++){
        float4 t = *(const float4*)&Bs[kk][c*64 + tx*4];
        bv[c*4+0]=t.x; bv[c*4+1]=t.y; bv[c*4+2]=t.z; bv[c*4+3]=t.w;
      }
      #pragma unroll
      for(int i = 0; i < CM*4; i++)
        #pragma unroll
        for(int j = 0; j < CN*4; j++)
          acc[i][j] += av[i]*bv[j];
    }
    __syncthreads();
  }
  #pragma unroll
  for(int ci = 0; ci < CM; ci++)
    #pragma unroll
    for(int i = 0; i < 4; i++){
      int row = rowbase + ci*64 + ty*4 + i;
      if(row >= M) continue;
      #pragma unroll
      for(int cj = 0; cj < CN; cj++)
        #pragma unroll
        for(int j = 0; j < 4; j++){
          int colg = colbase + cj*64 + tx*4 + j;
          if(colg >= N) continue;
          float v = acc[ci*4+i][cj*4+j];
          if(bias) v += bias[colg];
          C[(size_t)row*ldc + colg] = v;
        }
    }
}

// ---------------- GAT aggregate: one wave per dst node, CSR ----------------
// out[n] = elu( (sum_e exp(e-m)*hs[src_e]) / (sum_e exp(e-m)) + bias ),  H=4 heads
template<int D>
__global__ __launch_bounds__(256) void gat_aggregate(
    const float* __restrict__ hs, const float* __restrict__ el,
    const float* __restrict__ er, const int* __restrict__ ofs,
    const int* __restrict__ colv, const float* __restrict__ bias,
    float* __restrict__ outv, int Nd){
  const int F = 4*D, R = F/64;
  int node = blockIdx.x*4 + (threadIdx.x >> 6);
  int lane = threadIdx.x & 63;
  if(node >= Nd) return;
  int e0 = ofs[node], e1 = ofs[node+1];
  const float4 erv = *(const float4*)(er + (size_t)node*4);
  // pass 1: per-head max of leaky_relu(el[src]+er[dst]) (lane-parallel over edges)
  float m0=-INFINITY, m1=-INFINITY, m2=-INFINITY, m3=-INFINITY;
  for(int i = e0 + lane; i < e1; i += 64){
    int s = colv[i];
    float4 ev = *(const float4*)(el + (size_t)s*4);
    float x0 = ev.x + erv.x; x0 = x0 > 0.f ? x0 : 0.2f*x0;
    float x1 = ev.y + erv.y; x1 = x1 > 0.f ? x1 : 0.2f*x1;
    float x2 = ev.z + erv.z; x2 = x2 > 0.f ? x2 : 0.2f*x2;
    float x3 = ev.w + erv.w; x3 = x3 > 0.f ? x3 : 0.2f*x3;
    m0 = fmaxf(m0,x0); m1 = fmaxf(m1,x1); m2 = fmaxf(m2,x2); m3 = fmaxf(m3,x3);
  }
  #pragma unroll
  for(int off = 32; off; off >>= 1){
    m0 = fmaxf(m0, __shfl_xor(m0, off));
    m1 = fmaxf(m1, __shfl_xor(m1, off));
    m2 = fmaxf(m2, __shfl_xor(m2, off));
    m3 = fmaxf(m3, __shfl_xor(m3, off));
  }
  // pass 2: weighted aggregate (whole wave per edge, coalesced hs row)
  float acc[R];
  #pragma unroll
  for(int r = 0; r < R; r++) acc[r] = 0.f;
  float s0=0.f, s1=0.f, s2=0.f, s3=0.f;
  for(int i = e0; i < e1; i++){
    int s = colv[i];
    float4 ev = *(const float4*)(el + (size_t)s*4);  // same addr all lanes: broadcast
    float x0 = ev.x + erv.x; x0 = x0 > 0.f ? x0 : 0.2f*x0;
    float x1 = ev.y + erv.y; x1 = x1 > 0.f ? x1 : 0.2f*x1;
    float x2 = ev.z + erv.z; x2 = x2 > 0.f ? x2 : 0.2f*x2;
    float x3 = ev.w + erv.w; x3 = x3 > 0.f ? x3 : 0.2f*x3;
    float w0 = __expf(x0 - m0), w1 = __expf(x1 - m1);
    float w2 = __expf(x2 - m2), w3 = __expf(x3 - m3);
    s0 += w0; s1 += w1; s2 += w2; s3 += w3;
    const float* hrow = hs + (size_t)s*F;
    if constexpr (D == 128){
      #pragma unroll
      for(int r = 0; r < R; r++){
        const int h = r >> 1;  // compile-time head index
        float w = h==0 ? w0 : (h==1 ? w1 : (h==2 ? w2 : w3));
        acc[r] += w * hrow[lane + r*64];
      }
    } else {  // D == 32, R == 2
      float wa = (lane & 32) ? w1 : w0;
      float wb = (lane & 32) ? w3 : w2;
      acc[0] += wa * hrow[lane];
      acc[1] += wb * hrow[lane + 64];
    }
  }
  // epilogue: normalize, +bias, elu
  float d0 = (s0 == 0.f) ? 1.f : s0;
  float d1 = (s1 == 0.f) ? 1.f : s1;
  float d2 = (s2 == 0.f) ? 1.f : s2;
  float d3 = (s3 == 0.f) ? 1.f : s3;
  #pragma unroll
  for(int r = 0; r < R; r++){
    int idx = lane + r*64;
    float den;
    if constexpr (D == 128){
      const int h = r >> 1;
      den = h==0 ? d0 : (h==1 ? d1 : (h==2 ? d2 : d3));
    } else {
      den = (r == 0) ? ((lane & 32) ? d1 : d0) : ((lane & 32) ? d3 : d2);
    }
    float v = acc[r]/den + bias[idx];
    v = v > 0.f ? v : (__expf(v) - 1.f);
    outv[(size_t)node*F + idx] = v;
  }
}

// ---------------- host orchestration ----------------
extern "C" void kernel_launch(void* const* d_in, const int* in_sizes, int n_in,
                              void* d_out, int out_size, void* d_ws, size_t ws_size,
                              hipStream_t stream){
  const float* hp   = (const float*)d_in[0];
  const float* hq   = (const float*)d_in[1];
  const float* hk   = (const float*)d_in[2];
  const float* ha   = (const float*)d_in[3];
  const int* meta_src = (const int*)d_in[4];
  const int* meta_dst = (const int*)d_in[5];
  const int* q_src = (const int*)d_in[6];
  const int* q_dst = (const int*)d_in[7];
  const int* k_src = (const int*)d_in[8];
  const int* k_dst = (const int*)d_in[9];
  const int* a_src = (const int*)d_in[10];
  const int* a_dst = (const int*)d_in[11];
  const float* W0  = (const float*)d_in[12]; const float* al0 = (const float*)d_in[13];
  const float* ar0 = (const float*)d_in[14]; const float* b0  = (const float*)d_in[15];
  const float* W1  = (const float*)d_in[16]; const float* al1 = (const float*)d_in[17];
  const float* ar1 = (const float*)d_in[18]; const float* b1  = (const float*)d_in[19];
  const float* Wq  = (const float*)d_in[20]; const float* alq = (const float*)d_in[21];
  const float* arq = (const float*)d_in[22]; const float* bq  = (const float*)d_in[23];
  const float* Wkw = (const float*)d_in[24]; const float* alkw= (const float*)d_in[25];
  const float* arkw= (const float*)d_in[26]; const float* bkw = (const float*)d_in[27];
  const float* Watt= (const float*)d_in[28]; const float* alatt=(const float*)d_in[29];
  const float* aratt=(const float*)d_in[30]; const float* batt= (const float*)d_in[31];
  const float* Wpnn_a = (const float*)d_in[32];
  const float* Wpn_a  = (const float*)d_in[33];
  const float* Wpnn   = (const float*)d_in[34];
  const float* Wpn    = (const float*)d_in[35];
  const float* Wpred  = (const float*)d_in[36];
  const float* bpred  = (const float*)d_in[37];
  (void)n_in; (void)out_size; (void)ws_size;

  const int IN = 128, ATT = 64;
  const int NP = in_sizes[0]/IN, NQ = in_sizes[1]/ATT, NK = in_sizes[2]/ATT, NA = in_sizes[3]/ATT;
  const int EM = in_sizes[4], EQ = in_sizes[6], EK = in_sizes[8], EA = in_sizes[10];

  // ----- workspace layout -----
  uint8_t* wp = (uint8_t*)d_ws;
  auto alloc = [&](size_t bytes)->uint8_t*{
    uint8_t* p = wp; wp += (bytes + 255) & ~(size_t)255; return p;
  };
  float* hcat = (float*)alloc((size_t)NP*256*4);
  float* hbuf = (float*)alloc((size_t)NP*128*4);
  float* hpd  = (float*)alloc((size_t)NP*64*4);
  int NSmax = NQ > NK ? NQ : NK; if(NA > NSmax) NSmax = NA;
  float* proj = (float*)alloc((size_t)NSmax*64*4);
  float* el   = (float*)alloc((size_t)NP*4*4);
  float* er   = (float*)alloc((size_t)NP*4*4);
  float* wfa  = (float*)alloc(512*4);
  float* wfb  = (float*)alloc(512*4);
  int* cnt    = (int*)alloc((size_t)(NP+1)*4);
  int* cursor = (int*)alloc((size_t)(NP+1)*4);
  int* ofsm   = (int*)alloc((size_t)(NP+1)*4);
  int* ofsq   = (int*)alloc((size_t)(NP+1)*4);
  int* ofsk   = (int*)alloc((size_t)(NP+1)*4);
  int* ofsa   = (int*)alloc((size_t)(NP+1)*4);
  int* colm   = (int*)alloc((size_t)EM*4);
  int* colq   = (int*)alloc((size_t)EQ*4);
  int* colk   = (int*)alloc((size_t)EK*4);
  int* cola   = (int*)alloc((size_t)EA*4);

  // big staging buffers live inside d_out (dead until final GEMM writes it):
  // o: NP*512 floats, hs: up to NK*512 floats -> 40.96M floats <= 50M = out_size
  float* o_buf  = (float*)d_out;
  float* hs_buf = o_buf + (size_t)NP*512;

  auto gemm128 = [&](const float* A, const float* B, const float* bias, float* C,
                     int M, int N, int K, int lda, int ldb, int ldc){
    dim3 g((M+127)/128, (N+127)/128);
    gemm_k<128,128><<<g, 256, 0, stream>>>(A, B, bias, C, M, N, K, lda, ldb, ldc);
  };
  auto gemm64 = [&](const float* A, const float* B, const float* bias, float* C,
                    int M, int N, int K, int lda, int ldb, int ldc){
    dim3 g((M+63)/64, (N+63)/64);
    gemm_k<64,64><<<g, 256, 0, stream>>>(A, B, bias, C, M, N, K, lda, ldb, ldc);
  };
  auto build = [&](const int* s, const int* d, int E, int* ofs, int* colv){
    fill_zero_i32<<<(NP+255)/256, 256, 0, stream>>>(cnt, NP);
    count_dst_k<<<(E+255)/256, 256, 0, stream>>>(d, E, cnt);
    scan_excl_k<<<1, 1024, 0, stream>>>(cnt, ofs, cursor, NP);
    scatter_k<<<(E+255)/256, 256, 0, stream>>>(s, d, E, cursor, colv);
  };

  // ----- CSR for all 4 graphs -----
  build(meta_src, meta_dst, EM, ofsm, colm);
  build(q_src, q_dst, EQ, ofsq, colq);
  build(k_src, k_dst, EK, ofsk, colk);
  build(a_src, a_dst, EA, ofsa, cola);

  // ----- metapath GAT layer 0 -----
  gemm128(hp, W0, nullptr, hs_buf, NP, 128, 128, 128, 128, 128);
  fold_k<<<2, 256, 0, stream>>>(W0, al0, wfa, 128, 32);
  fold_k<<<2, 256, 0, stream>>>(W0, ar0, wfb, 128, 32);
  gemv4_k<<<(NP+3)/4, 256, 0, stream>>>(hp, wfa, el, NP, 128, 128);
  gemv4_k<<<(NP+3)/4, 256, 0, stream>>>(hp, wfb, er, NP, 128, 128);
  gat_aggregate<32><<<(NP+3)/4, 256, 0, stream>>>(hs_buf, el, er, ofsm, colm, b0, hbuf, NP);

  // ----- metapath GAT layer 1 -----
  gemm128(hbuf, W1, nullptr, hs_buf, NP, 128, 128, 128, 128, 128);
  fold_k<<<2, 256, 0, stream>>>(W1, al1, wfa, 128, 32);
  fold_k<<<2, 256, 0, stream>>>(W1, ar1, wfb, 128, 32);
  gemv4_k<<<(NP+3)/4, 256, 0, stream>>>(hbuf, wfa, el, NP, 128, 128);
  gemv4_k<<<(NP+3)/4, 256, 0, stream>>>(hbuf, wfb, er, NP, 128, 128);
  gat_aggregate<32><<<(NP+3)/4, 256, 0, stream>>>(hs_buf, el, er, ofsm, colm, b1, hbuf, NP);

  // ----- hcat[:,0:64] = h @ Wpnn -----
  gemm64(hbuf, Wpnn, nullptr, hcat, NP, 64, 128, 128, 64, 256);
  // ----- hpd = hp @ Wpnn_a -----
  gemm64(hp, Wpnn_a, nullptr, hpd, NP, 64, 128, 128, 64, 64);

  // ----- bipartite GATs -----
  auto bip = [&](const float* feat, int Ns, const int* ofs, const int* colv,
                 const float* W, const float* alp, const float* arp, const float* bb,
                 int colofs){
    gemm64(feat, Wpn_a, nullptr, proj, Ns, 64, 64, 64, 64, 64);
    gemm128(proj, W, nullptr, hs_buf, Ns, 512, 64, 64, 512, 512);
    fold_k<<<1, 256, 0, stream>>>(W, alp, wfa, 64, 128);
    fold_k<<<1, 256, 0, stream>>>(W, arp, wfb, 64, 128);
    gemv4_k<<<(Ns+3)/4, 256, 0, stream>>>(proj, wfa, el, Ns, 64, 64);
    gemv4_k<<<(NP+3)/4, 256, 0, stream>>>(hpd, wfb, er, NP, 64, 64);
    gat_aggregate<128><<<(NP+3)/4, 256, 0, stream>>>(hs_buf, el, er, ofs, colv, bb, o_buf, NP);
    gemm64(o_buf, Wpn, nullptr, hcat + colofs, NP, 64, 512, 512, 64, 256);
  };
  bip(hq, NQ, ofsq, colq, Wq,  alq,  arq,  bq,  64);
  bip(hk, NK, ofsk, colk, Wkw, alkw, arkw, bkw, 128);
  bip(ha, NA, ofsa, cola, Watt,alatt,aratt,batt,192);

  // ----- final: out = hcat @ Wpred + bpred -----
  gemm128(hcat, Wpred, bpred, (float*)d_out, NP, 1000, 256, 256, 1000, 1000);
}

// Round 2
// 2543.949 us; speedup vs baseline: 1.0057x; 1.0057x over previous
//
#include <hip/hip_runtime.h>
#include <hip/hip_bf16.h>
#include <math.h>
#include <stdint.h>

// ---------------- CSR build ----------------
__global__ void fill_zero_i32(int* __restrict__ p, int n){
  int i = blockIdx.x*blockDim.x + threadIdx.x;
  if(i < n) p[i] = 0;
}

__global__ void count_dst_k(const int* __restrict__ dst, int E, int* __restrict__ cnt){
  int i = blockIdx.x*blockDim.x + threadIdx.x;
  if(i < E) atomicAdd(&cnt[dst[i]], 1);
}

__global__ __launch_bounds__(1024) void scan_excl_k(const int* __restrict__ cnt,
    int* __restrict__ ofs, int* __restrict__ cursor, int n){
  __shared__ int tmp[1024];
  __shared__ int carry_s;
  int tid = threadIdx.x;
  if(tid == 0) carry_s = 0;
  __syncthreads();
  for(int base = 0; base < n; base += 1024){
    int i = base + tid;
    int v = (i < n) ? cnt[i] : 0;
    tmp[tid] = v;
    __syncthreads();
    for(int off = 1; off < 1024; off <<= 1){
      int t = (tid >= off) ? tmp[tid-off] : 0;
      __syncthreads();
      tmp[tid] += t;
      __syncthreads();
    }
    if(i < n){ int e = tmp[tid] - v + carry_s; ofs[i] = e; cursor[i] = e; }
    __syncthreads();
    if(tid == 0) carry_s += tmp[1023];
    __syncthreads();
  }
  if(tid == 0) ofs[n] = carry_s;
}

__global__ void scatter_k(const int* __restrict__ src, const int* __restrict__ dst,
    int E, int* __restrict__ cursor, int* __restrict__ colv){
  int i = blockIdx.x*blockDim.x + threadIdx.x;
  if(i < E){ int p = atomicAdd(&cursor[dst[i]], 1); colv[p] = src[i]; }
}

// ---------------- attention-weight fold: Wf[k,h] = sum_d W[k, h*D+d]*a[h,d] ----------------
__global__ void fold_k(const float* __restrict__ W, const float* __restrict__ a,
    float* __restrict__ Wf, int K, int D){
  int i = blockIdx.x*blockDim.x + threadIdx.x;
  if(i >= K*4) return;
  int k = i >> 2, h = i & 3;
  const float* wr = W + (size_t)k*4*D + (size_t)h*D;
  const float* ar = a + (size_t)h*D;
  float s = 0.f;
  for(int d = 0; d < D; d++) s += wr[d]*ar[d];
  Wf[k*4 + h] = s;
}

// ---------------- out[m,0:4] = A[m,:] @ Wf[:,0:4]  (one wave per row) ----------------
__global__ __launch_bounds__(256) void gemv4_k(const float* __restrict__ A,
    const float* __restrict__ Wf, float* __restrict__ outv, int M, int K, int lda){
  int wid = (blockIdx.x*blockDim.x + threadIdx.x) >> 6;
  int lane = threadIdx.x & 63;
  if(wid >= M) return;
  const float* arow = A + (size_t)wid*lda;
  float a0=0.f, a1=0.f, a2=0.f, a3=0.f;
  for(int k = lane; k < K; k += 64){
    float av = arow[k];
    float4 w = *(const float4*)(Wf + k*4);
    a0 += av*w.x; a1 += av*w.y; a2 += av*w.z; a3 += av*w.w;
  }
  #pragma unroll
  for(int off = 32; off; off >>= 1){
    a0 += __shfl_down(a0, off); a1 += __shfl_down(a1, off);
    a2 += __shfl_down(a2, off); a3 += __shfl_down(a3, off);
  }
  if(lane == 0){
    float4 r; r.x=a0; r.y=a1; r.z=a2; r.w=a3;
    *(float4*)(outv + (size_t)wid*4) = r;
  }
}

// ---------------- tiled fp32 GEMM: C[M,N] = A[M,K] @ B[K,N] (+bias) ----------------
template<int TM, int TN>
__global__ __launch_bounds__(256) void gemm_k(const float* __restrict__ A,
    const float* __restrict__ B, const float* __restrict__ bias, float* __restrict__ C,
    int M, int N, int K, int lda, int ldb, int ldc){
  const int CM = TM/64, CN = TN/64;
  __shared__ float As[16][TM+4];
  __shared__ float Bs[16][TN+4];
  int tid = threadIdx.x;
  int tx = tid & 15, ty = tid >> 4;
  int rowbase = blockIdx.x*TM, colbase = blockIdx.y*TN;
  float acc[CM*4][CN*4];
  #pragma unroll
  for(int i = 0; i < CM*4; i++)
    #pragma unroll
    for(int j = 0; j < CN*4; j++) acc[i][j] = 0.f;

  for(int k0 = 0; k0 < K; k0 += 16){
    for(int idx = tid; idx < TM*16; idx += 256){
      int r = idx >> 4, kk = idx & 15;
      int row = rowbase + r;
      As[kk][r] = (row < M) ? A[(size_t)row*lda + (k0+kk)] : 0.f;
    }
    for(int idx = tid; idx < 16*TN; idx += 256){
      int kk = idx / TN, c = idx % TN;
      int colg = colbase + c;
      Bs[kk][c] = (colg < N) ? B[(size_t)(k0+kk)*ldb + colg] : 0.f;
    }
    __syncthreads();
    #pragma unroll
    for(int kk = 0; kk < 16; kk++){
      float av[CM*4], bv[CN*4];
      #pragma unroll
      for(int c = 0; c < CM; c++){
        float4 t = *(const float4*)&As[kk][c*64 + ty*4];
        av[c*4+0]=t.x; av[c*4+1]=t.y; av[c*4+2]=t.z; av[c*4+3]=t.w;
      }
      #pragma unroll
      for(int c = 0; c < CN; c++){
        float4 t = *(const float4*)&Bs[kk][c*64 + tx*4];
        bv[c*4+0]=t.x; bv[c*4+1]=t.y; bv[c*4+2]=t.z; bv[c*4+3]=t.w;
      }
      #pragma unroll
      for(int i = 0; i < CM*4; i++)
        #pragma unroll
        for(int j = 0; j < CN*4; j++)
          acc[i][j] += av[i]*bv[j];
    }
    __syncthreads();
  }
  #pragma unroll
  for(int ci = 0; ci < CM; ci++)
    #pragma unroll
    for(int i = 0; i < 4; i++){
      int row = rowbase + ci*64 + ty*4 + i;
      if(row >= M) continue;
      #pragma unroll
      for(int cj = 0; cj < CN; cj++)
        #pragma unroll
        for(int j = 0; j < 4; j++){
          int colg = colbase + cj*64 + tx*4 + j;
          if(colg >= N) continue;
          float v = acc[ci*4+i][cj*4+j];
          if(bias) v += bias[colg];
          C[(size_t)row*ldc + colg] = v;
        }
    }
}

// ---------------- GAT aggregate: one wave per dst node, CSR ----------------
// out[n] = elu( (sum_e exp(e-m)*hs[src_e]) / (sum_e exp(e-m)) + bias ),  H=4 heads
template<int D>
__global__ __launch_bounds__(256) void gat_aggregate(
    const float* __restrict__ hs, const float* __restrict__ el,
    const float* __restrict__ er, const int* __restrict__ ofs,
    const int* __restrict__ colv, const float* __restrict__ bias,
    float* __restrict__ outv, int Nd){
  const int F = 4*D, R = F/64;
  int node = blockIdx.x*4 + (threadIdx.x >> 6);
  int lane = threadIdx.x & 63;
  if(node >= Nd) return;
  int e0 = ofs[node], e1 = ofs[node+1];
  const float4 erv = *(const float4*)(er + (size_t)node*4);
  // pass 1: per-head max of leaky_relu(el[src]+er[dst]) (lane-parallel over edges)
  float m0=-INFINITY, m1=-INFINITY, m2=-INFINITY, m3=-INFINITY;
  for(int i = e0 + lane; i < e1; i += 64){
    int s = colv[i];
    float4 ev = *(const float4*)(el + (size_t)s*4);
    float x0 = ev.x + erv.x; x0 = x0 > 0.f ? x0 : 0.2f*x0;
    float x1 = ev.y + erv.y; x1 = x1 > 0.f ? x1 : 0.2f*x1;
    float x2 = ev.z + erv.z; x2 = x2 > 0.f ? x2 : 0.2f*x2;
    float x3 = ev.w + erv.w; x3 = x3 > 0.f ? x3 : 0.2f*x3;
    m0 = fmaxf(m0,x0); m1 = fmaxf(m1,x1); m2 = fmaxf(m2,x2); m3 = fmaxf(m3,x3);
  }
  #pragma unroll
  for(int off = 32; off; off >>= 1){
    m0 = fmaxf(m0, __shfl_xor(m0, off));
    m1 = fmaxf(m1, __shfl_xor(m1, off));
    m2 = fmaxf(m2, __shfl_xor(m2, off));
    m3 = fmaxf(m3, __shfl_xor(m3, off));
  }
  // pass 2: weighted aggregate (whole wave per edge, coalesced hs row)
  float acc[R];
  #pragma unroll
  for(int r = 0; r < R; r++) acc[r] = 0.f;
  float s0=0.f, s1=0.f, s2=0.f, s3=0.f;
  for(int i = e0; i < e1; i++){
    int s = colv[i];
    float4 ev = *(const float4*)(el + (size_t)s*4);  // same addr all lanes: broadcast
    float x0 = ev.x + erv.x; x0 = x0 > 0.f ? x0 : 0.2f*x0;
    float x1 = ev.y + erv.y; x1 = x1 > 0.f ? x1 : 0.2f*x1;
    float x2 = ev.z + erv.z; x2 = x2 > 0.f ? x2 : 0.2f*x2;
    float x3 = ev.w + erv.w; x3 = x3 > 0.f ? x3 : 0.2f*x3;
    float w0 = __expf(x0 - m0), w1 = __expf(x1 - m1);
    float w2 = __expf(x2 - m2), w3 = __expf(x3 - m3);
    s0 += w0; s1 += w1; s2 += w2; s3 += w3;
    const float* hrow = hs + (size_t)s*F;
    if constexpr (D == 128){
      #pragma unroll
      for(int r = 0; r < R; r++){
        const int h = r >> 1;  // compile-time head index
        float w = h==0 ? w0 : (h==1 ? w1 : (h==2 ? w2 : w3));
        acc[r] += w * hrow[lane + r*64];
      }
    } else {  // D == 32, R == 2
      float wa = (lane & 32) ? w1 : w0;
      float wb = (lane & 32) ? w3 : w2;
      acc[0] += wa * hrow[lane];
      acc[1] += wb * hrow[lane + 64];
    }
  }
  // epilogue: normalize, +bias, elu
  float d0 = (s0 == 0.f) ? 1.f : s0;
  float d1 = (s1 == 0.f) ? 1.f : s1;
  float d2 = (s2 == 0.f) ? 1.f : s2;
  float d3 = (s3 == 0.f) ? 1.f : s3;
  #pragma unroll
  for(int r = 0; r < R; r++){
    int idx = lane + r*64;
    float den;
    if constexpr (D == 128){
      const int h = r >> 1;
      den = h==0 ? d0 : (h==1 ? d1 : (h==2 ? d2 : d3));
    } else {
      den = (r == 0) ? ((lane & 32) ? d1 : d0) : ((lane & 32) ? d3 : d2);
    }
    float v = acc[r]/den + bias[idx];
    v = v > 0.f ? v : (__expf(v) - 1.f);
    outv[(size_t)node*F + idx] = v;
  }
}

// ---------------- host orchestration ----------------
extern "C" void kernel_launch(void* const* d_in, const int* in_sizes, int n_in,
                              void* d_out, int out_size, void* d_ws, size_t ws_size,
                              hipStream_t stream){
  const float* hp   = (const float*)d_in[0];
  const float* hq   = (const float*)d_in[1];
  const float* hk   = (const float*)d_in[2];
  const float* ha   = (const float*)d_in[3];
  const int* meta_src = (const int*)d_in[4];
  const int* meta_dst = (const int*)d_in[5];
  const int* q_src = (const int*)d_in[6];
  const int* q_dst = (const int*)d_in[7];
  const int* k_src = (const int*)d_in[8];
  const int* k_dst = (const int*)d_in[9];
  const int* a_src = (const int*)d_in[10];
  const int* a_dst = (const int*)d_in[11];
  const float* W0  = (const float*)d_in[12]; const float* al0 = (const float*)d_in[13];
  const float* ar0 = (const float*)d_in[14]; const float* b0  = (const float*)d_in[15];
  const float* W1  = (const float*)d_in[16]; const float* al1 = (const float*)d_in[17];
  const float* ar1 = (const float*)d_in[18]; const float* b1  = (const float*)d_in[19];
  const float* Wq  = (const float*)d_in[20]; const float* alq = (const float*)d_in[21];
  const float* arq = (const float*)d_in[22]; const float* bq  = (const float*)d_in[23];
  const float* Wkw = (const float*)d_in[24]; const float* alkw= (const float*)d_in[25];
  const float* arkw= (const float*)d_in[26]; const float* bkw = (const float*)d_in[27];
  const float* Watt= (const float*)d_in[28]; const float* alatt=(const float*)d_in[29];
  const float* aratt=(const float*)d_in[30]; const float* batt= (const float*)d_in[31];
  const float* Wpnn_a = (const float*)d_in[32];
  const float* Wpn_a  = (const float*)d_in[33];
  const float* Wpnn   = (const float*)d_in[34];
  const float* Wpn    = (const float*)d_in[35];
  const float* Wpred  = (const float*)d_in[36];
  const float* bpred  = (const float*)d_in[37];
  (void)n_in; (void)out_size; (void)ws_size;

  const int IN = 128, ATT = 64;
  const int NP = in_sizes[0]/IN, NQ = in_sizes[1]/ATT, NK = in_sizes[2]/ATT, NA = in_sizes[3]/ATT;
  const int EM = in_sizes[4], EQ = in_sizes[6], EK = in_sizes[8], EA = in_sizes[10];

  // ----- workspace layout -----
  uint8_t* wp = (uint8_t*)d_ws;
  auto alloc = [&](size_t bytes)->uint8_t*{
    uint8_t* p = wp; wp += (bytes + 255) & ~(size_t)255; return p;
  };
  float* hcat = (float*)alloc((size_t)NP*256*4);
  float* hbuf = (float*)alloc((size_t)NP*128*4);
  float* hpd  = (float*)alloc((size_t)NP*64*4);
  int NSmax = NQ > NK ? NQ : NK; if(NA > NSmax) NSmax = NA;
  float* proj = (float*)alloc((size_t)NSmax*64*4);
  float* el   = (float*)alloc((size_t)NP*4*4);
  float* er   = (float*)alloc((size_t)NP*4*4);
  float* wfa  = (float*)alloc(512*4);
  float* wfb  = (float*)alloc(512*4);
  int* cnt    = (int*)alloc((size_t)(NP+1)*4);
  int* cursor = (int*)alloc((size_t)(NP+1)*4);
  int* ofsm   = (int*)alloc((size_t)(NP+1)*4);
  int* ofsq   = (int*)alloc((size_t)(NP+1)*4);
  int* ofsk   = (int*)alloc((size_t)(NP+1)*4);
  int* ofsa   = (int*)alloc((size_t)(NP+1)*4);
  int* colm   = (int*)alloc((size_t)EM*4);
  int* colq   = (int*)alloc((size_t)EQ*4);
  int* colk   = (int*)alloc((size_t)EK*4);
  int* cola   = (int*)alloc((size_t)EA*4);

  // big staging buffers live inside d_out (dead until final GEMM writes it):
  // o: NP*512 floats, hs: up to NK*512 floats -> 40.96M floats <= 50M = out_size
  float* o_buf  = (float*)d_out;
  float* hs_buf = o_buf + (size_t)NP*512;

  auto gemm128 = [&](const float* A, const float* B, const float* bias, float* C,
                     int M, int N, int K, int lda, int ldb, int ldc){
    dim3 g((M+127)/128, (N+127)/128);
    gemm_k<128,128><<<g, 256, 0, stream>>>(A, B, bias, C, M, N, K, lda, ldb, ldc);
  };
  auto gemm64 = [&](const float* A, const float* B, const float* bias, float* C,
                    int M, int N, int K, int lda, int ldb, int ldc){
    dim3 g((M+63)/64, (N+63)/64);
    gemm_k<64,64><<<g, 256, 0, stream>>>(A, B, bias, C, M, N, K, lda, ldb, ldc);
  };
  auto build = [&](const int* s, const int* d, int E, int* ofs, int* colv){
    fill_zero_i32<<<(NP+255)/256, 256, 0, stream>>>(cnt, NP);
    count_dst_k<<<(E+255)/256, 256, 0, stream>>>(d, E, cnt);
    scan_excl_k<<<1, 1024, 0, stream>>>(cnt, ofs, cursor, NP);
    scatter_k<<<(E+255)/256, 256, 0, stream>>>(s, d, E, cursor, colv);
  };

  // ----- CSR for all 4 graphs -----
  build(meta_src, meta_dst, EM, ofsm, colm);
  build(q_src, q_dst, EQ, ofsq, colq);
  build(k_src, k_dst, EK, ofsk, colk);
  build(a_src, a_dst, EA, ofsa, cola);

  // ----- metapath GAT layer 0 -----
  gemm128(hp, W0, nullptr, hs_buf, NP, 128, 128, 128, 128, 128);
  fold_k<<<2, 256, 0, stream>>>(W0, al0, wfa, 128, 32);
  fold_k<<<2, 256, 0, stream>>>(W0, ar0, wfb, 128, 32);
  gemv4_k<<<(NP+3)/4, 256, 0, stream>>>(hp, wfa, el, NP, 128, 128);
  gemv4_k<<<(NP+3)/4, 256, 0, stream>>>(hp, wfb, er, NP, 128, 128);
  gat_aggregate<32><<<(NP+3)/4, 256, 0, stream>>>(hs_buf, el, er, ofsm, colm, b0, hbuf, NP);

  // ----- metapath GAT layer 1 -----
  gemm128(hbuf, W1, nullptr, hs_buf, NP, 128, 128, 128, 128, 128);
  fold_k<<<2, 256, 0, stream>>>(W1, al1, wfa, 128, 32);
  fold_k<<<2, 256, 0, stream>>>(W1, ar1, wfb, 128, 32);
  gemv4_k<<<(NP+3)/4, 256, 0, stream>>>(hbuf, wfa, el, NP, 128, 128);
  gemv4_k<<<(NP+3)/4, 256, 0, stream>>>(hbuf, wfb, er, NP, 128, 128);
  gat_aggregate<32><<<(NP+3)/4, 256, 0, stream>>>(hs_buf, el, er, ofsm, colm, b1, hbuf, NP);

  // ----- hcat[:,0:64] = h @ Wpnn -----
  gemm64(hbuf, Wpnn, nullptr, hcat, NP, 64, 128, 128, 64, 256);
  // ----- hpd = hp @ Wpnn_a -----
  gemm64(hp, Wpnn_a, nullptr, hpd, NP, 64, 128, 128, 64, 64);

  // ----- bipartite GATs -----
  auto bip = [&](const float* feat, int Ns, const int* ofs, const int* colv,
                 const float* W, const float* alp, const float* arp, const float* bb,
                 int colofs){
    gemm64(feat, Wpn_a, nullptr, proj, Ns, 64, 64, 64, 64, 64);
    gemm128(proj, W, nullptr, hs_buf, Ns, 512, 64, 64, 512, 512);
    fold_k<<<1, 256, 0, stream>>>(W, alp, wfa, 64, 128);
    fold_k<<<1, 256, 0, stream>>>(W, arp, wfb, 64, 128);
    gemv4_k<<<(Ns+3)/4, 256, 0, stream>>>(proj, wfa, el, Ns, 64, 64);
    gemv4_k<<<(NP+3)/4, 256, 0, stream>>>(hpd, wfb, er, NP, 64, 64);
    gat_aggregate<128><<<(NP+3)/4, 256, 0, stream>>>(hs_buf, el, er, ofs, colv, bb, o_buf, NP);
    gemm64(o_buf, Wpn, nullptr, hcat + colofs, NP, 64, 512, 512, 64, 256);
  };
  bip(hq, NQ, ofsq, colq, Wq,  alq,  arq,  bq,  64);
  bip(hk, NK, ofsk, colk, Wkw, alkw, arkw, bkw, 128);
  bip(ha, NA, ofsa, cola, Watt,alatt,aratt,batt,192);

  // ----- final: out = hcat @ Wpred + bpred -----
  gemm128(hcat, Wpred, bpred, (float*)d_out, NP, 1000, 256, 256, 1000, 1000);
}

// Round 3
// 1713.251 us; speedup vs baseline: 1.4934x; 1.4849x over previous
//
#include <hip/hip_runtime.h>
#include <hip/hip_bf16.h>
#include <math.h>
#include <stdint.h>

typedef __attribute__((ext_vector_type(8))) short bh8;
typedef __attribute__((ext_vector_type(4))) float f32x4;

#define AS1(p) ((const __attribute__((address_space(1))) void*)(p))
#define AS3(p) ((__attribute__((address_space(3))) void*)(p))

__device__ inline ushort f2b(float f){
  uint u = __builtin_bit_cast(uint, f);
  u += 0x7fff + ((u >> 16) & 1);
  return (ushort)(u >> 16);
}
__device__ inline float b2f(ushort b){ return __builtin_bit_cast(float, (uint)b << 16); }

// ---------------- CSR build ----------------
__global__ void fill_zero_i32(int* __restrict__ p, int n){
  int i = blockIdx.x*blockDim.x + threadIdx.x;
  if(i < n) p[i] = 0;
}

__global__ void count_dst_k(const int* __restrict__ dst, int E, int* __restrict__ cnt){
  int i = blockIdx.x*blockDim.x + threadIdx.x;
  if(i < E) atomicAdd(&cnt[dst[i]], 1);
}

__global__ __launch_bounds__(1024) void scan_excl_k(const int* __restrict__ cnt,
    int* __restrict__ ofs, int* __restrict__ cursor, int n){
  __shared__ int tmp[1024];
  __shared__ int carry_s;
  int tid = threadIdx.x;
  if(tid == 0) carry_s = 0;
  __syncthreads();
  for(int base = 0; base < n; base += 1024){
    int i = base + tid;
    int v = (i < n) ? cnt[i] : 0;
    tmp[tid] = v;
    __syncthreads();
    for(int off = 1; off < 1024; off <<= 1){
      int t = (tid >= off) ? tmp[tid-off] : 0;
      __syncthreads();
      tmp[tid] += t;
      __syncthreads();
    }
    if(i < n){ int e = tmp[tid] - v + carry_s; ofs[i] = e; cursor[i] = e; }
    __syncthreads();
    if(tid == 0) carry_s += tmp[1023];
    __syncthreads();
  }
  if(tid == 0) ofs[n] = carry_s;
}

__global__ void scatter_k(const int* __restrict__ src, const int* __restrict__ dst,
    int E, int* __restrict__ cursor, int* __restrict__ colv){
  int i = blockIdx.x*blockDim.x + threadIdx.x;
  if(i < E){ int p = atomicAdd(&cursor[dst[i]], 1); colv[p] = src[i]; }
}

// ---------------- fp32 -> bf16 convert (vectorized x4) ----------------
__global__ void f2b_vec(const float* __restrict__ in, ushort* __restrict__ out, int n4){
  int i = blockIdx.x*blockDim.x + threadIdx.x;
  if(i >= n4) return;
  float4 v = ((const float4*)in)[i];
  ushort4 o; o.x = f2b(v.x); o.y = f2b(v.y); o.z = f2b(v.z); o.w = f2b(v.w);
  ((ushort4*)out)[i] = o;
}

// ---------------- weight transpose + convert: WT[n][k] = bf16(W[k][n]), n padded ----------------
__global__ void wT_k(const float* __restrict__ W, ushort* __restrict__ WT,
    int K, int N, int Npad){
  int idx = blockIdx.x*blockDim.x + threadIdx.x;
  if(idx >= Npad*K) return;
  int n = idx / K, k = idx - n*K;
  WT[idx] = (n < N) ? f2b(W[(size_t)k*N + n]) : (ushort)0;
}

// ---------------- attention-weight fold: Wf[k,h] = sum_d W[k, h*D+d]*a[h,d] ----------------
__global__ void fold_k(const float* __restrict__ W, const float* __restrict__ a,
    float* __restrict__ Wf, int K, int D){
  int i = blockIdx.x*blockDim.x + threadIdx.x;
  if(i >= K*4) return;
  int k = i >> 2, h = i & 3;
  const float* wr = W + (size_t)k*4*D + (size_t)h*D;
  const float* ar = a + (size_t)h*D;
  float s = 0.f;
  for(int d = 0; d < D; d++) s += wr[d]*ar[d];
  Wf[k*4 + h] = s;
}

// ---------------- out[m,0:4] = A[m,:] @ Wf[:,0:4]  (one wave per row) ----------------
__device__ inline float ldval(const float* p){ return *p; }
__device__ inline float ldval(const ushort* p){ return b2f(*p); }

template<typename T>
__global__ __launch_bounds__(256) void gemv4_t(const T* __restrict__ A,
    const float* __restrict__ Wf, float* __restrict__ outv, int M, int K, int lda){
  int wid = (blockIdx.x*blockDim.x + threadIdx.x) >> 6;
  int lane = threadIdx.x & 63;
  if(wid >= M) return;
  const T* arow = A + (size_t)wid*lda;
  float a0=0.f, a1=0.f, a2=0.f, a3=0.f;
  for(int k = lane; k < K; k += 64){
    float av = ldval(arow + k);
    float4 w = *(const float4*)(Wf + k*4);
    a0 += av*w.x; a1 += av*w.y; a2 += av*w.z; a3 += av*w.w;
  }
  #pragma unroll
  for(int off = 32; off; off >>= 1){
    a0 += __shfl_down(a0, off); a1 += __shfl_down(a1, off);
    a2 += __shfl_down(a2, off); a3 += __shfl_down(a3, off);
  }
  if(lane == 0){
    float4 r; r.x=a0; r.y=a1; r.z=a2; r.w=a3;
    *(float4*)(outv + (size_t)wid*4) = r;
  }
}

// ---------------- bf16 MFMA GEMM: C[M,N] = A[M,K](bf16) @ BT[Npad,K](bf16)^T ----------------
// BM=128, BK=64, 4 waves (2x2). LDS slot-swizzle: elem (r,k) at byte
// r*128 + ((k>>3)^(r&7))*16 + (k&7)*2  -> staged by pre-swizzling the GLOBAL source.
template<int BN, typename OutT, bool BIAS>
__global__ __launch_bounds__(256) void gemm_mfma(
    const ushort* __restrict__ A, const ushort* __restrict__ BT,
    const float* __restrict__ bias, OutT* __restrict__ C,
    int M, int N, int K, int lda, int ldc){
  constexpr int BM = 128, BK = 64;
  constexpr int NI = BN/32;                 // frags per wave in N
  constexpr int AIT = BM*BK/(256*8);        // = 4
  constexpr int BIT = BN*BK/(256*8);        // 4 (BN=128) or 2 (BN=64)
  __shared__ ushort lds[BM*BK + BN*BK];
  ushort* ldsA = lds;
  ushort* ldsB = lds + BM*BK;
  const int tid = threadIdx.x, wid = tid >> 6, lane = tid & 63;
  const int wr = wid >> 1, wc = wid & 1;
  const int rowbase = blockIdx.x*BM, colbase = blockIdx.y*BN;

  f32x4 acc[4][NI];
  #pragma unroll
  for(int mi = 0; mi < 4; mi++)
    #pragma unroll
    for(int ni = 0; ni < NI; ni++) acc[mi][ni] = (f32x4)0.f;

  for(int k0 = 0; k0 < K; k0 += BK){
    #pragma unroll
    for(int it = 0; it < AIT; it++){
      int idx = it*256 + wid*64 + lane;
      int r = idx >> 3, sl = idx & 7;
      int kb = sl ^ (r & 7);
      int grow = rowbase + r; if(grow >= M) grow = M-1;
      const ushort* src = A + (size_t)grow*lda + k0 + kb*8;
      __builtin_amdgcn_global_load_lds(AS1(src), AS3(ldsA + (size_t)(it*256 + wid*64)*8), 16, 0, 0);
    }
    #pragma unroll
    for(int it = 0; it < BIT; it++){
      int idx = it*256 + wid*64 + lane;
      int r = idx >> 3, sl = idx & 7;
      int kb = sl ^ (r & 7);
      const ushort* src = BT + (size_t)(colbase + r)*K + k0 + kb*8;
      __builtin_amdgcn_global_load_lds(AS1(src), AS3(ldsB + (size_t)(it*256 + wid*64)*8), 16, 0, 0);
    }
    __syncthreads();
    #pragma unroll
    for(int kk = 0; kk < 2; kk++){
      bh8 af[4], bf[NI];
      #pragma unroll
      for(int mi = 0; mi < 4; mi++){
        int arow = wr*64 + mi*16 + (lane & 15);
        int kb = kk*4 + (lane >> 4);
        af[mi] = *(const bh8*)(ldsA + arow*BK + ((kb ^ (arow & 7)) << 3));
      }
      #pragma unroll
      for(int ni = 0; ni < NI; ni++){
        int brow = wc*(BN/2) + ni*16 + (lane & 15);
        int kb = kk*4 + (lane >> 4);
        bf[ni] = *(const bh8*)(ldsB + brow*BK + ((kb ^ (brow & 7)) << 3));
      }
      #pragma unroll
      for(int mi = 0; mi < 4; mi++)
        #pragma unroll
        for(int ni = 0; ni < NI; ni++)
          acc[mi][ni] = __builtin_amdgcn_mfma_f32_16x16x32_bf16(af[mi], bf[ni], acc[mi][ni], 0, 0, 0);
    }
    __syncthreads();
  }
  // epilogue: C/D frag layout col=lane&15, row=(lane>>4)*4+j (m89-verified)
  #pragma unroll
  for(int mi = 0; mi < 4; mi++){
    #pragma unroll
    for(int ni = 0; ni < NI; ni++){
      int col = colbase + wc*(BN/2) + ni*16 + (lane & 15);
      if(col >= N) continue;
      float bv = BIAS ? bias[col] : 0.f;
      #pragma unroll
      for(int j = 0; j < 4; j++){
        int row = rowbase + wr*64 + mi*16 + (lane >> 4)*4 + j;
        if(row >= M) continue;
        float v = acc[mi][ni][j] + bv;
        if constexpr (sizeof(OutT) == 4) C[(size_t)row*ldc + col] = v;
        else                             C[(size_t)row*ldc + col] = (OutT)f2b(v);
      }
    }
  }
}

// ---------------- GAT aggregate (bf16 hs/out): one wave per dst node ----------------
template<int D>
__global__ __launch_bounds__(256) void gat_agg_b(
    const ushort* __restrict__ hs, const float* __restrict__ el,
    const float* __restrict__ er, const int* __restrict__ ofs,
    const int* __restrict__ colv, const float* __restrict__ bias,
    ushort* __restrict__ outv, int Nd){
  const int node = blockIdx.x*4 + (threadIdx.x >> 6);
  const int lane = threadIdx.x & 63;
  if(node >= Nd) return;
  const int e0 = ofs[node], e1 = ofs[node+1];
  const float4 erv = *(const float4*)(er + (size_t)node*4);
  // pass 1: per-head max (lane-parallel over edges)
  float m0=-INFINITY, m1=-INFINITY, m2=-INFINITY, m3=-INFINITY;
  for(int i = e0 + lane; i < e1; i += 64){
    int s = colv[i];
    float4 ev = *(const float4*)(el + (size_t)s*4);
    float x0 = ev.x + erv.x; x0 = x0 > 0.f ? x0 : 0.2f*x0;
    float x1 = ev.y + erv.y; x1 = x1 > 0.f ? x1 : 0.2f*x1;
    float x2 = ev.z + erv.z; x2 = x2 > 0.f ? x2 : 0.2f*x2;
    float x3 = ev.w + erv.w; x3 = x3 > 0.f ? x3 : 0.2f*x3;
    m0 = fmaxf(m0,x0); m1 = fmaxf(m1,x1); m2 = fmaxf(m2,x2); m3 = fmaxf(m3,x3);
  }
  #pragma unroll
  for(int off = 32; off; off >>= 1){
    m0 = fmaxf(m0, __shfl_xor(m0, off));
    m1 = fmaxf(m1, __shfl_xor(m1, off));
    m2 = fmaxf(m2, __shfl_xor(m2, off));
    m3 = fmaxf(m3, __shfl_xor(m3, off));
  }
  const int h = lane >> 4;  // owning head of this lane's feature slice
  const float mh = h==0 ? m0 : (h==1 ? m1 : (h==2 ? m2 : m3));
  const float erh = h==0 ? erv.x : (h==1 ? erv.y : (h==2 ? erv.z : erv.w));
  // pass 2: weighted aggregate (whole wave per edge, coalesced bf16 row)
  constexpr int R = (D == 128) ? 8 : 2;
  float acc[R];
  #pragma unroll
  for(int r = 0; r < R; r++) acc[r] = 0.f;
  float ssum = 0.f;
  for(int i = e0; i < e1; i++){
    int s = colv[i];
    float4 ev = *(const float4*)(el + (size_t)s*4);  // broadcast
    float evh = h==0 ? ev.x : (h==1 ? ev.y : (h==2 ? ev.z : ev.w));
    float x = evh + erh; x = x > 0.f ? x : 0.2f*x;
    float w = __expf(x - mh);
    ssum += w;
    if constexpr (D == 128){
      bh8 hv = *(const bh8*)(hs + (size_t)s*512 + lane*8);
      #pragma unroll
      for(int r = 0; r < 8; r++) acc[r] += w * b2f((ushort)hv[r]);
    } else {
      uint hv = *(const uint*)(hs + (size_t)s*128 + lane*2);
      acc[0] += w * b2f((ushort)(hv & 0xffffu));
      acc[1] += w * b2f((ushort)(hv >> 16));
    }
  }
  float den = (ssum == 0.f) ? 1.f : ssum;
  if constexpr (D == 128){
    bh8 ov;
    #pragma unroll
    for(int r = 0; r < 8; r++){
      float v = acc[r]/den + bias[lane*8 + r];
      v = v > 0.f ? v : (__expf(v) - 1.f);
      ov[r] = (short)f2b(v);
    }
    *(bh8*)(outv + (size_t)node*512 + lane*8) = ov;
  } else {
    float v0 = acc[0]/den + bias[lane*2 + 0];
    float v1 = acc[1]/den + bias[lane*2 + 1];
    v0 = v0 > 0.f ? v0 : (__expf(v0) - 1.f);
    v1 = v1 > 0.f ? v1 : (__expf(v1) - 1.f);
    uint pack = (uint)f2b(v0) | ((uint)f2b(v1) << 16);
    *(uint*)(outv + (size_t)node*128 + lane*2) = pack;
  }
}

// ---------------- host orchestration ----------------
extern "C" void kernel_launch(void* const* d_in, const int* in_sizes, int n_in,
                              void* d_out, int out_size, void* d_ws, size_t ws_size,
                              hipStream_t stream){
  const float* hp   = (const float*)d_in[0];
  const float* hq   = (const float*)d_in[1];
  const float* hk   = (const float*)d_in[2];
  const float* ha   = (const float*)d_in[3];
  const int* meta_src = (const int*)d_in[4];
  const int* meta_dst = (const int*)d_in[5];
  const int* q_src = (const int*)d_in[6];
  const int* q_dst = (const int*)d_in[7];
  const int* k_src = (const int*)d_in[8];
  const int* k_dst = (const int*)d_in[9];
  const int* a_src = (const int*)d_in[10];
  const int* a_dst = (const int*)d_in[11];
  const float* W0  = (const float*)d_in[12]; const float* al0 = (const float*)d_in[13];
  const float* ar0 = (const float*)d_in[14]; const float* b0  = (const float*)d_in[15];
  const float* W1  = (const float*)d_in[16]; const float* al1 = (const float*)d_in[17];
  const float* ar1 = (const float*)d_in[18]; const float* b1  = (const float*)d_in[19];
  const float* Wq  = (const float*)d_in[20]; const float* alq = (const float*)d_in[21];
  const float* arq = (const float*)d_in[22]; const float* bq  = (const float*)d_in[23];
  const float* Wkw = (const float*)d_in[24]; const float* alkw= (const float*)d_in[25];
  const float* arkw= (const float*)d_in[26]; const float* bkw = (const float*)d_in[27];
  const float* Watt= (const float*)d_in[28]; const float* alatt=(const float*)d_in[29];
  const float* aratt=(const float*)d_in[30]; const float* batt= (const float*)d_in[31];
  const float* Wpnn_a = (const float*)d_in[32];
  const float* Wpn_a  = (const float*)d_in[33];
  const float* Wpnn   = (const float*)d_in[34];
  const float* Wpn    = (const float*)d_in[35];
  const float* Wpred  = (const float*)d_in[36];
  const float* bpred  = (const float*)d_in[37];
  (void)n_in; (void)out_size; (void)ws_size;

  const int IN = 128, ATT = 64;
  const int NP = in_sizes[0]/IN, NQ = in_sizes[1]/ATT, NK = in_sizes[2]/ATT, NA = in_sizes[3]/ATT;
  const int EM = in_sizes[4], EQ = in_sizes[6], EK = in_sizes[8], EA = in_sizes[10];

  // ----- workspace layout -----
  uint8_t* wp = (uint8_t*)d_ws;
  auto alloc = [&](size_t bytes)->uint8_t*{
    uint8_t* p = wp; wp += (bytes + 255) & ~(size_t)255; return p;
  };
  ushort* hcat_b = (ushort*)alloc((size_t)NP*256*2);
  ushort* hbuf_b = (ushort*)alloc((size_t)NP*128*2);
  ushort* hp_b   = (ushort*)alloc((size_t)NP*128*2);
  float*  hpd    = (float*)alloc((size_t)NP*64*4);
  int NSmax = NQ > NK ? NQ : NK; if(NA > NSmax) NSmax = NA;
  ushort* proj_b = (ushort*)alloc((size_t)NSmax*64*2);
  ushort* fq_b   = (ushort*)alloc((size_t)NQ*64*2);
  ushort* fk_b   = (ushort*)alloc((size_t)NK*64*2);
  ushort* fa_b   = (ushort*)alloc((size_t)NA*64*2);
  float* el   = (float*)alloc((size_t)NP*4*4);
  float* er   = (float*)alloc((size_t)NP*4*4);
  float* wfa  = (float*)alloc(512*4);
  float* wfb  = (float*)alloc(512*4);
  int* cnt    = (int*)alloc((size_t)(NP+1)*4);
  int* cursor = (int*)alloc((size_t)(NP+1)*4);
  int* ofsm   = (int*)alloc((size_t)(NP+1)*4);
  int* ofsq   = (int*)alloc((size_t)(NP+1)*4);
  int* ofsk   = (int*)alloc((size_t)(NP+1)*4);
  int* ofsa   = (int*)alloc((size_t)(NP+1)*4);
  int* colm   = (int*)alloc((size_t)EM*4);
  int* colq   = (int*)alloc((size_t)EQ*4);
  int* colk   = (int*)alloc((size_t)EK*4);
  int* cola   = (int*)alloc((size_t)EA*4);
  // transposed bf16 weights [Npad][K]
  ushort* W0T    = (ushort*)alloc(128*128*2);
  ushort* W1T    = (ushort*)alloc(128*128*2);
  ushort* WqT    = (ushort*)alloc(512*64*2);
  ushort* WkwT   = (ushort*)alloc(512*64*2);
  ushort* WattT  = (ushort*)alloc(512*64*2);
  ushort* WpnT   = (ushort*)alloc((size_t)64*512*2);
  ushort* WpnnT  = (ushort*)alloc(64*128*2);
  ushort* Wpnn_aT= (ushort*)alloc(64*128*2);
  ushort* Wpn_aT = (ushort*)alloc(64*64*2);
  ushort* WpredT = (ushort*)alloc((size_t)1024*256*2);

  // big bf16 staging in d_out (dead until final GEMM): o 25.6M us + hs <=15.36M us
  ushort* o_b  = (ushort*)d_out;
  ushort* hs_b = o_b + (size_t)NP*512;

  auto cvt = [&](const float* in, ushort* out, size_t n){
    int n4 = (int)(n/4);
    f2b_vec<<<(n4+255)/256, 256, 0, stream>>>(in, out, n4);
  };
  auto wT = [&](const float* W, ushort* WT, int K, int N, int Npad){
    int tot = Npad*K;
    wT_k<<<(tot+255)/256, 256, 0, stream>>>(W, WT, K, N, Npad);
  };
  auto build = [&](const int* s, const int* d, int E, int* ofs, int* colv){
    fill_zero_i32<<<(NP+255)/256, 256, 0, stream>>>(cnt, NP);
    count_dst_k<<<(E+255)/256, 256, 0, stream>>>(d, E, cnt);
    scan_excl_k<<<1, 1024, 0, stream>>>(cnt, ofs, cursor, NP);
    scatter_k<<<(E+255)/256, 256, 0, stream>>>(s, d, E, cursor, colv);
  };
  auto gemm = [&]<int BN, typename OutT, bool BIAS>(const ushort* A, const ushort* BT,
      const float* bias, OutT* C, int M, int N, int K, int lda, int ldc){
    int Npad = (N + BN - 1)/BN*BN;
    dim3 g((M + 127)/128, Npad/BN);
    gemm_mfma<BN, OutT, BIAS><<<g, 256, 0, stream>>>(A, BT, bias, C, M, N, K, lda, ldc);
  };

  // ----- CSR + conversions -----
  build(meta_src, meta_dst, EM, ofsm, colm);
  build(q_src, q_dst, EQ, ofsq, colq);
  build(k_src, k_dst, EK, ofsk, colk);
  build(a_src, a_dst, EA, ofsa, cola);
  cvt(hp, hp_b, (size_t)NP*128);
  cvt(hq, fq_b, (size_t)NQ*64);
  cvt(hk, fk_b, (size_t)NK*64);
  cvt(ha, fa_b, (size_t)NA*64);
  wT(W0, W0T, 128, 128, 128);      wT(W1, W1T, 128, 128, 128);
  wT(Wq, WqT, 64, 512, 512);       wT(Wkw, WkwT, 64, 512, 512);
  wT(Watt, WattT, 64, 512, 512);   wT(Wpn, WpnT, 512, 64, 64);
  wT(Wpnn, WpnnT, 128, 64, 64);    wT(Wpnn_a, Wpnn_aT, 128, 64, 64);
  wT(Wpn_a, Wpn_aT, 64, 64, 64);   wT(Wpred, WpredT, 256, 1000, 1024);

  // ----- metapath GAT layer 0 -----
  gemm.template operator()<128, ushort, false>(hp_b, W0T, nullptr, hs_b, NP, 128, 128, 128, 128);
  fold_k<<<2, 256, 0, stream>>>(W0, al0, wfa, 128, 32);
  fold_k<<<2, 256, 0, stream>>>(W0, ar0, wfb, 128, 32);
  gemv4_t<float><<<(NP+3)/4, 256, 0, stream>>>(hp, wfa, el, NP, 128, 128);
  gemv4_t<float><<<(NP+3)/4, 256, 0, stream>>>(hp, wfb, er, NP, 128, 128);
  gat_agg_b<32><<<(NP+3)/4, 256, 0, stream>>>(hs_b, el, er, ofsm, colm, b0, hbuf_b, NP);

  // ----- metapath GAT layer 1 -----
  gemm.template operator()<128, ushort, false>(hbuf_b, W1T, nullptr, hs_b, NP, 128, 128, 128, 128);
  fold_k<<<2, 256, 0, stream>>>(W1, al1, wfa, 128, 32);
  fold_k<<<2, 256, 0, stream>>>(W1, ar1, wfb, 128, 32);
  gemv4_t<ushort><<<(NP+3)/4, 256, 0, stream>>>(hbuf_b, wfa, el, NP, 128, 128);
  gemv4_t<ushort><<<(NP+3)/4, 256, 0, stream>>>(hbuf_b, wfb, er, NP, 128, 128);
  gat_agg_b<32><<<(NP+3)/4, 256, 0, stream>>>(hs_b, el, er, ofsm, colm, b1, hbuf_b, NP);

  // ----- hcat[:,0:64] = h @ Wpnn ; hpd = hp @ Wpnn_a -----
  gemm.template operator()<64, ushort, false>(hbuf_b, WpnnT, nullptr, hcat_b, NP, 64, 128, 128, 256);
  gemm.template operator()<64, float, false>(hp_b, Wpnn_aT, nullptr, hpd, NP, 64, 128, 128, 64);

  // ----- bipartite GATs -----
  auto bip = [&](const ushort* feat_b, int Ns, const int* ofs, const int* colv,
                 const float* W, const ushort* WT_, const float* alp, const float* arp,
                 const float* bb, int colofs){
    gemm.template operator()<64, ushort, false>(feat_b, Wpn_aT, nullptr, proj_b, Ns, 64, 64, 64, 64);
    gemm.template operator()<128, ushort, false>(proj_b, WT_, nullptr, hs_b, Ns, 512, 64, 64, 512);
    fold_k<<<1, 256, 0, stream>>>(W, alp, wfa, 64, 128);
    fold_k<<<1, 256, 0, stream>>>(W, arp, wfb, 64, 128);
    gemv4_t<ushort><<<(Ns+3)/4, 256, 0, stream>>>(proj_b, wfa, el, Ns, 64, 64);
    gemv4_t<float><<<(NP+3)/4, 256, 0, stream>>>(hpd, wfb, er, NP, 64, 64);
    gat_agg_b<128><<<(NP+3)/4, 256, 0, stream>>>(hs_b, el, er, ofs, colv, bb, o_b, NP);
    gemm.template operator()<64, ushort, false>(o_b, WpnT, nullptr, hcat_b + colofs, NP, 64, 512, 512, 256);
  };
  bip(fq_b, NQ, ofsq, colq, Wq,  WqT,  alq,  arq,  bq,  64);
  bip(fk_b, NK, ofsk, colk, Wkw, WkwT, alkw, arkw, bkw, 128);
  bip(fa_b, NA, ofsa, cola, Watt,WattT,alatt,aratt,batt,192);

  // ----- final: out = hcat @ Wpred + bpred -----
  gemm.template operator()<128, float, true>(hcat_b, WpredT, bpred, (float*)d_out, NP, 1000, 256, 256, 1000);
}

// Round 4
// 1272.592 us; speedup vs baseline: 2.0105x; 1.3463x over previous
//
#include <hip/hip_runtime.h>
#include <hip/hip_bf16.h>
#include <math.h>
#include <stdint.h>

typedef __attribute__((ext_vector_type(8))) short bh8;
typedef __attribute__((ext_vector_type(4))) float f32x4;

#define AS1(p) ((const __attribute__((address_space(1))) void*)(p))
#define AS3(p) ((__attribute__((address_space(3))) void*)(p))

__device__ inline ushort f2b(float f){
  uint u = __builtin_bit_cast(uint, f);
  u += 0x7fff + ((u >> 16) & 1);
  return (ushort)(u >> 16);
}
__device__ inline float b2f(ushort b){ return __builtin_bit_cast(float, (uint)b << 16); }

// ---------------- CSR build ----------------
__global__ void fill_zero_i32(int* __restrict__ p, int n){
  int i = blockIdx.x*blockDim.x + threadIdx.x;
  if(i < n) p[i] = 0;
}

__global__ void count_dst_k(const int* __restrict__ dst, int E, int* __restrict__ cnt){
  int i = blockIdx.x*blockDim.x + threadIdx.x;
  if(i < E) atomicAdd(&cnt[dst[i]], 1);
}

__global__ __launch_bounds__(1024) void scan_excl_k(const int* __restrict__ cnt,
    int* __restrict__ ofs, int* __restrict__ cursor, int n){
  __shared__ int wsum[16];
  __shared__ int carry_s;
  int tid = threadIdx.x, wid = tid >> 6, lane = tid & 63;
  if(tid == 0) carry_s = 0;
  __syncthreads();
  for(int base = 0; base < n; base += 1024){
    int i = base + tid;
    int v = (i < n) ? cnt[i] : 0;
    int x = v;
    #pragma unroll
    for(int off = 1; off < 64; off <<= 1){
      int t = __shfl_up(x, off);
      if(lane >= off) x += t;
    }
    if(lane == 63) wsum[wid] = x;
    __syncthreads();
    if(tid < 16){
      int y = wsum[tid];
      #pragma unroll
      for(int off = 1; off < 16; off <<= 1){
        int t = __shfl_up(y, off);
        if(tid >= off) y += t;
      }
      wsum[tid] = y;
    }
    __syncthreads();
    int wpre = wid ? wsum[wid-1] : 0;
    if(i < n){ int e = x - v + wpre + carry_s; ofs[i] = e; cursor[i] = e; }
    __syncthreads();
    if(tid == 0) carry_s += wsum[15];
    __syncthreads();
  }
  if(tid == 0) ofs[n] = carry_s;
}

__global__ void scatter_k(const int* __restrict__ src, const int* __restrict__ dst,
    int E, int* __restrict__ cursor, int* __restrict__ colv){
  int i = blockIdx.x*blockDim.x + threadIdx.x;
  if(i < E){ int p = atomicAdd(&cursor[dst[i]], 1); colv[p] = src[i]; }
}

// ---------------- fp32 -> bf16 convert (vectorized x4) ----------------
__global__ void f2b_vec(const float* __restrict__ in, ushort* __restrict__ out, int n4){
  int i = blockIdx.x*blockDim.x + threadIdx.x;
  if(i >= n4) return;
  float4 v = ((const float4*)in)[i];
  ushort4 o; o.x = f2b(v.x); o.y = f2b(v.y); o.z = f2b(v.z); o.w = f2b(v.w);
  ((ushort4*)out)[i] = o;
}

// ---------------- weight transpose + convert: WT[n][k] = bf16(W[k][n]), n padded ----------------
__global__ void wT_k(const float* __restrict__ W, ushort* __restrict__ WT,
    int K, int N, int Npad){
  int idx = blockIdx.x*blockDim.x + threadIdx.x;
  if(idx >= Npad*K) return;
  int n = idx / K, k = idx - n*K;
  WT[idx] = (n < N) ? f2b(W[(size_t)k*N + n]) : (ushort)0;
}

// ---------------- attention-weight fold: Wf[k,h] = sum_d W[k, h*D+d]*a[h,d] ----------------
__global__ void fold_k(const float* __restrict__ W, const float* __restrict__ a,
    float* __restrict__ Wf, int K, int D){
  int i = blockIdx.x*blockDim.x + threadIdx.x;
  if(i >= K*4) return;
  int k = i >> 2, h = i & 3;
  const float* wr = W + (size_t)k*4*D + (size_t)h*D;
  const float* ar = a + (size_t)h*D;
  float s = 0.f;
  for(int d = 0; d < D; d++) s += wr[d]*ar[d];
  Wf[k*4 + h] = s;
}

__device__ inline float ldval(const float* p){ return *p; }
__device__ inline float ldval(const ushort* p){ return b2f(*p); }

// ---------------- out[m,0:4] = A[m,:] @ Wf[:,0:4]  (one wave per row) ----------------
template<typename T>
__global__ __launch_bounds__(256) void gemv4_t(const T* __restrict__ A,
    const float* __restrict__ Wf, float* __restrict__ outv, int M, int K, int lda){
  int wid = (blockIdx.x*blockDim.x + threadIdx.x) >> 6;
  int lane = threadIdx.x & 63;
  if(wid >= M) return;
  const T* arow = A + (size_t)wid*lda;
  float a0=0.f, a1=0.f, a2=0.f, a3=0.f;
  for(int k = lane; k < K; k += 64){
    float av = ldval(arow + k);
    float4 w = *(const float4*)(Wf + k*4);
    a0 += av*w.x; a1 += av*w.y; a2 += av*w.z; a3 += av*w.w;
  }
  #pragma unroll
  for(int off = 32; off; off >>= 1){
    a0 += __shfl_down(a0, off); a1 += __shfl_down(a1, off);
    a2 += __shfl_down(a2, off); a3 += __shfl_down(a3, off);
  }
  if(lane == 0){
    float4 r; r.x=a0; r.y=a1; r.z=a2; r.w=a3;
    *(float4*)(outv + (size_t)wid*4) = r;
  }
}

// ---------------- fused dual gemv: el = A@Wfa, er = A@Wfb ----------------
template<typename T>
__global__ __launch_bounds__(256) void gemv8_t(const T* __restrict__ A,
    const float* __restrict__ Wfa, const float* __restrict__ Wfb,
    float* __restrict__ oa, float* __restrict__ ob, int M, int K, int lda){
  int wid = (blockIdx.x*blockDim.x + threadIdx.x) >> 6;
  int lane = threadIdx.x & 63;
  if(wid >= M) return;
  const T* arow = A + (size_t)wid*lda;
  float a0=0.f,a1=0.f,a2=0.f,a3=0.f,b0=0.f,b1=0.f,b2=0.f,b3=0.f;
  for(int k = lane; k < K; k += 64){
    float av = ldval(arow + k);
    float4 wa = *(const float4*)(Wfa + k*4);
    float4 wb = *(const float4*)(Wfb + k*4);
    a0 += av*wa.x; a1 += av*wa.y; a2 += av*wa.z; a3 += av*wa.w;
    b0 += av*wb.x; b1 += av*wb.y; b2 += av*wb.z; b3 += av*wb.w;
  }
  #pragma unroll
  for(int off = 32; off; off >>= 1){
    a0 += __shfl_down(a0, off); a1 += __shfl_down(a1, off);
    a2 += __shfl_down(a2, off); a3 += __shfl_down(a3, off);
    b0 += __shfl_down(b0, off); b1 += __shfl_down(b1, off);
    b2 += __shfl_down(b2, off); b3 += __shfl_down(b3, off);
  }
  if(lane == 0){
    float4 r; r.x=a0; r.y=a1; r.z=a2; r.w=a3;
    *(float4*)(oa + (size_t)wid*4) = r;
    float4 s; s.x=b0; s.y=b1; s.z=b2; s.w=b3;
    *(float4*)(ob + (size_t)wid*4) = s;
  }
}

// ---------------- bf16 MFMA GEMM: C[M,N] = A[M,K](bf16) @ BT[Npad,K](bf16)^T ----------------
template<int BN, typename OutT, bool BIAS>
__global__ __launch_bounds__(256) void gemm_mfma(
    const ushort* __restrict__ A, const ushort* __restrict__ BT,
    const float* __restrict__ bias, OutT* __restrict__ C,
    int M, int N, int K, int lda, int ldc){
  constexpr int BM = 128, BK = 64;
  constexpr int NI = BN/32;
  constexpr int AIT = BM*BK/(256*8);
  constexpr int BIT = BN*BK/(256*8);
  __shared__ ushort lds[BM*BK + BN*BK];
  ushort* ldsA = lds;
  ushort* ldsB = lds + BM*BK;
  const int tid = threadIdx.x, wid = tid >> 6, lane = tid & 63;
  const int wr = wid >> 1, wc = wid & 1;
  const int rowbase = blockIdx.x*BM, colbase = blockIdx.y*BN;

  f32x4 acc[4][NI];
  #pragma unroll
  for(int mi = 0; mi < 4; mi++)
    #pragma unroll
    for(int ni = 0; ni < NI; ni++) acc[mi][ni] = (f32x4)0.f;

  for(int k0 = 0; k0 < K; k0 += BK){
    #pragma unroll
    for(int it = 0; it < AIT; it++){
      int idx = it*256 + wid*64 + lane;
      int r = idx >> 3, sl = idx & 7;
      int kb = sl ^ (r & 7);
      int grow = rowbase + r; if(grow >= M) grow = M-1;
      const ushort* src = A + (size_t)grow*lda + k0 + kb*8;
      __builtin_amdgcn_global_load_lds(AS1(src), AS3(ldsA + (size_t)(it*256 + wid*64)*8), 16, 0, 0);
    }
    #pragma unroll
    for(int it = 0; it < BIT; it++){
      int idx = it*256 + wid*64 + lane;
      int r = idx >> 3, sl = idx & 7;
      int kb = sl ^ (r & 7);
      const ushort* src = BT + (size_t)(colbase + r)*K + k0 + kb*8;
      __builtin_amdgcn_global_load_lds(AS1(src), AS3(ldsB + (size_t)(it*256 + wid*64)*8), 16, 0, 0);
    }
    __syncthreads();
    #pragma unroll
    for(int kk = 0; kk < 2; kk++){
      bh8 af[4], bf[NI];
      #pragma unroll
      for(int mi = 0; mi < 4; mi++){
        int arow = wr*64 + mi*16 + (lane & 15);
        int kb = kk*4 + (lane >> 4);
        af[mi] = *(const bh8*)(ldsA + arow*BK + ((kb ^ (arow & 7)) << 3));
      }
      #pragma unroll
      for(int ni = 0; ni < NI; ni++){
        int brow = wc*(BN/2) + ni*16 + (lane & 15);
        int kb = kk*4 + (lane >> 4);
        bf[ni] = *(const bh8*)(ldsB + brow*BK + ((kb ^ (brow & 7)) << 3));
      }
      #pragma unroll
      for(int mi = 0; mi < 4; mi++)
        #pragma unroll
        for(int ni = 0; ni < NI; ni++)
          acc[mi][ni] = __builtin_amdgcn_mfma_f32_16x16x32_bf16(af[mi], bf[ni], acc[mi][ni], 0, 0, 0);
    }
    __syncthreads();
  }
  #pragma unroll
  for(int mi = 0; mi < 4; mi++){
    #pragma unroll
    for(int ni = 0; ni < NI; ni++){
      int col = colbase + wc*(BN/2) + ni*16 + (lane & 15);
      if(col >= N) continue;
      float bv = BIAS ? bias[col] : 0.f;
      #pragma unroll
      for(int j = 0; j < 4; j++){
        int row = rowbase + wr*64 + mi*16 + (lane >> 4)*4 + j;
        if(row >= M) continue;
        float v = acc[mi][ni][j] + bv;
        if constexpr (sizeof(OutT) == 4) C[(size_t)row*ldc + col] = v;
        else                             C[(size_t)row*ldc + col] = (OutT)f2b(v);
      }
    }
  }
}

// ---------------- GAT aggregate v2: chunked online-softmax, MLP-friendly ----------------
// One wave per dst node. Per 64-edge chunk: lane-parallel weight computation with
// flash-style (m, sum, acc) rescale, {src,w[4]} staged in LDS, then an unrolled
// aggregation loop with U independent row loads in flight.
template<int D>
__global__ __launch_bounds__(256) void gat_agg2(
    const ushort* __restrict__ hs, const float* __restrict__ el,
    const float* __restrict__ er, const int* __restrict__ ofs,
    const int* __restrict__ colv, const float* __restrict__ bias,
    ushort* __restrict__ outv, int Nd){
  constexpr int R = (D == 128) ? 8 : 2;   // features per lane
  constexpr int U = (D == 128) ? 4 : 8;   // inner unroll (loads in flight)
  const int wslot = threadIdx.x >> 6;
  const int node = blockIdx.x*4 + wslot;
  const int lane = threadIdx.x & 63;
  __shared__ int   lds_s[4][64];
  __shared__ float lds_w[4][256];
  if(node >= Nd) return;
  const int e0 = ofs[node], e1 = ofs[node+1];
  const int h = lane >> 4;                // owning head of this lane's features
  const float4 erv = *(const float4*)(er + (size_t)node*4);
  float m0=-INFINITY, m1=-INFINITY, m2=-INFINITY, m3=-INFINITY;
  float sw0=0.f, sw1=0.f, sw2=0.f, sw3=0.f;
  float acc[R];
  #pragma unroll
  for(int r = 0; r < R; r++) acc[r] = 0.f;

  for(int base = e0; base < e1; base += 64){
    int nch = e1 - base; if(nch > 64) nch = 64;
    int s_l = colv[base + (lane < nch ? lane : nch-1)];
    float4 ev = *(const float4*)(el + (size_t)s_l*4);
    float x0 = ev.x + erv.x; x0 = x0 > 0.f ? x0 : 0.2f*x0;
    float x1 = ev.y + erv.y; x1 = x1 > 0.f ? x1 : 0.2f*x1;
    float x2 = ev.z + erv.z; x2 = x2 > 0.f ? x2 : 0.2f*x2;
    float x3 = ev.w + erv.w; x3 = x3 > 0.f ? x3 : 0.2f*x3;
    if(lane >= nch){ x0 = x1 = x2 = x3 = -INFINITY; }
    // chunk max per head
    float c0=x0, c1=x1, c2=x2, c3=x3;
    #pragma unroll
    for(int off = 32; off; off >>= 1){
      c0 = fmaxf(c0, __shfl_xor(c0, off));
      c1 = fmaxf(c1, __shfl_xor(c1, off));
      c2 = fmaxf(c2, __shfl_xor(c2, off));
      c3 = fmaxf(c3, __shfl_xor(c3, off));
    }
    float n0 = fmaxf(m0,c0), n1 = fmaxf(m1,c1), n2 = fmaxf(m2,c2), n3 = fmaxf(m3,c3);
    float r0 = __expf(m0-n0), r1 = __expf(m1-n1), r2 = __expf(m2-n2), r3 = __expf(m3-n3);
    float w0 = __expf(x0-n0), w1 = __expf(x1-n1), w2 = __expf(x2-n2), w3 = __expf(x3-n3);
    sw0 = sw0*r0 + w0; sw1 = sw1*r1 + w1; sw2 = sw2*r2 + w2; sw3 = sw3*r3 + w3;
    float rh = h==0 ? r0 : (h==1 ? r1 : (h==2 ? r2 : r3));
    #pragma unroll
    for(int r = 0; r < R; r++) acc[r] *= rh;
    m0=n0; m1=n1; m2=n2; m3=n3;
    lds_s[wslot][lane] = s_l;
    lds_w[wslot][lane*4+0] = w0; lds_w[wslot][lane*4+1] = w1;
    lds_w[wslot][lane*4+2] = w2; lds_w[wslot][lane*4+3] = w3;
    // padded entries (lane>=nch) have w==0, valid clamped s -> safe to include
    int npad = (nch + U-1) & ~(U-1);
    for(int j = 0; j < npad; j += U){
      #pragma unroll
      for(int u = 0; u < U; u++){
        int s = lds_s[wslot][j+u];
        float w = lds_w[wslot][(j+u)*4 + h];
        if constexpr (D == 128){
          bh8 hv = *(const bh8*)(hs + (size_t)s*512 + lane*8);
          #pragma unroll
          for(int r = 0; r < 8; r++) acc[r] += w * b2f((ushort)hv[r]);
        } else {
          uint hv = *(const uint*)(hs + (size_t)s*128 + lane*2);
          acc[0] += w * b2f((ushort)(hv & 0xffffu));
          acc[1] += w * b2f((ushort)(hv >> 16));
        }
      }
    }
  }
  // reduce per-lane partial head sums across the wave
  #pragma unroll
  for(int off = 32; off; off >>= 1){
    sw0 += __shfl_xor(sw0, off); sw1 += __shfl_xor(sw1, off);
    sw2 += __shfl_xor(sw2, off); sw3 += __shfl_xor(sw3, off);
  }
  float swh = h==0 ? sw0 : (h==1 ? sw1 : (h==2 ? sw2 : sw3));
  float den = (swh == 0.f) ? 1.f : swh;
  if constexpr (D == 128){
    bh8 ov;
    #pragma unroll
    for(int r = 0; r < 8; r++){
      float v = acc[r]/den + bias[lane*8 + r];
      v = v > 0.f ? v : (__expf(v) - 1.f);
      ov[r] = (short)f2b(v);
    }
    *(bh8*)(outv + (size_t)node*512 + lane*8) = ov;
  } else {
    float v0 = acc[0]/den + bias[lane*2 + 0];
    float v1 = acc[1]/den + bias[lane*2 + 1];
    v0 = v0 > 0.f ? v0 : (__expf(v0) - 1.f);
    v1 = v1 > 0.f ? v1 : (__expf(v1) - 1.f);
    *(uint*)(outv + (size_t)node*128 + lane*2) = (uint)f2b(v0) | ((uint)f2b(v1) << 16);
  }
}

// ---------------- host orchestration ----------------
extern "C" void kernel_launch(void* const* d_in, const int* in_sizes, int n_in,
                              void* d_out, int out_size, void* d_ws, size_t ws_size,
                              hipStream_t stream){
  const float* hp   = (const float*)d_in[0];
  const float* hq   = (const float*)d_in[1];
  const float* hk   = (const float*)d_in[2];
  const float* ha   = (const float*)d_in[3];
  const int* meta_src = (const int*)d_in[4];
  const int* meta_dst = (const int*)d_in[5];
  const int* q_src = (const int*)d_in[6];
  const int* q_dst = (const int*)d_in[7];
  const int* k_src = (const int*)d_in[8];
  const int* k_dst = (const int*)d_in[9];
  const int* a_src = (const int*)d_in[10];
  const int* a_dst = (const int*)d_in[11];
  const float* W0  = (const float*)d_in[12]; const float* al0 = (const float*)d_in[13];
  const float* ar0 = (const float*)d_in[14]; const float* b0  = (const float*)d_in[15];
  const float* W1  = (const float*)d_in[16]; const float* al1 = (const float*)d_in[17];
  const float* ar1 = (const float*)d_in[18]; const float* b1  = (const float*)d_in[19];
  const float* Wq  = (const float*)d_in[20]; const float* alq = (const float*)d_in[21];
  const float* arq = (const float*)d_in[22]; const float* bq  = (const float*)d_in[23];
  const float* Wkw = (const float*)d_in[24]; const float* alkw= (const float*)d_in[25];
  const float* arkw= (const float*)d_in[26]; const float* bkw = (const float*)d_in[27];
  const float* Watt= (const float*)d_in[28]; const float* alatt=(const float*)d_in[29];
  const float* aratt=(const float*)d_in[30]; const float* batt= (const float*)d_in[31];
  const float* Wpnn_a = (const float*)d_in[32];
  const float* Wpn_a  = (const float*)d_in[33];
  const float* Wpnn   = (const float*)d_in[34];
  const float* Wpn    = (const float*)d_in[35];
  const float* Wpred  = (const float*)d_in[36];
  const float* bpred  = (const float*)d_in[37];
  (void)n_in; (void)out_size; (void)ws_size;

  const int IN = 128, ATT = 64;
  const int NP = in_sizes[0]/IN, NQ = in_sizes[1]/ATT, NK = in_sizes[2]/ATT, NA = in_sizes[3]/ATT;
  const int EM = in_sizes[4], EQ = in_sizes[6], EK = in_sizes[8], EA = in_sizes[10];

  // ----- workspace layout -----
  uint8_t* wp = (uint8_t*)d_ws;
  auto alloc = [&](size_t bytes)->uint8_t*{
    uint8_t* p = wp; wp += (bytes + 255) & ~(size_t)255; return p;
  };
  ushort* hcat_b = (ushort*)alloc((size_t)NP*256*2);
  ushort* hbuf_b = (ushort*)alloc((size_t)NP*128*2);
  ushort* hp_b   = (ushort*)alloc((size_t)NP*128*2);
  ushort* hpd_b  = (ushort*)alloc((size_t)NP*64*2);
  int NSmax = NQ > NK ? NQ : NK; if(NA > NSmax) NSmax = NA;
  ushort* proj_b = (ushort*)alloc((size_t)NSmax*64*2);
  ushort* fq_b   = (ushort*)alloc((size_t)NQ*64*2);
  ushort* fk_b   = (ushort*)alloc((size_t)NK*64*2);
  ushort* fa_b   = (ushort*)alloc((size_t)NA*64*2);
  float* el   = (float*)alloc((size_t)NP*4*4);
  float* er   = (float*)alloc((size_t)NP*4*4);
  float* wfa  = (float*)alloc(512*4);
  float* wfb  = (float*)alloc(512*4);
  int* cnt    = (int*)alloc((size_t)(NP+1)*4);
  int* cursor = (int*)alloc((size_t)(NP+1)*4);
  int* ofsm   = (int*)alloc((size_t)(NP+1)*4);
  int* ofsq   = (int*)alloc((size_t)(NP+1)*4);
  int* ofsk   = (int*)alloc((size_t)(NP+1)*4);
  int* ofsa   = (int*)alloc((size_t)(NP+1)*4);
  int* colm   = (int*)alloc((size_t)EM*4);
  int* colq   = (int*)alloc((size_t)EQ*4);
  int* colk   = (int*)alloc((size_t)EK*4);
  int* cola   = (int*)alloc((size_t)EA*4);
  ushort* W0T    = (ushort*)alloc(128*128*2);
  ushort* W1T    = (ushort*)alloc(128*128*2);
  ushort* WqT    = (ushort*)alloc(512*64*2);
  ushort* WkwT   = (ushort*)alloc(512*64*2);
  ushort* WattT  = (ushort*)alloc(512*64*2);
  ushort* WpnT   = (ushort*)alloc((size_t)64*512*2);
  ushort* WpnnT  = (ushort*)alloc(64*128*2);
  ushort* Wpnn_aT= (ushort*)alloc(64*128*2);
  ushort* Wpn_aT = (ushort*)alloc(64*64*2);
  ushort* WpredT = (ushort*)alloc((size_t)1024*256*2);

  // big bf16 staging in d_out (dead until final GEMM writes it)
  ushort* o_b  = (ushort*)d_out;
  ushort* hs_b = o_b + (size_t)NP*512;

  auto cvt = [&](const float* in, ushort* out, size_t n){
    int n4 = (int)(n/4);
    f2b_vec<<<(n4+255)/256, 256, 0, stream>>>(in, out, n4);
  };
  auto wT = [&](const float* W, ushort* WT, int K, int N, int Npad){
    int tot = Npad*K;
    wT_k<<<(tot+255)/256, 256, 0, stream>>>(W, WT, K, N, Npad);
  };
  auto build = [&](const int* s, const int* d, int E, int* ofs, int* colv){
    fill_zero_i32<<<(NP+255)/256, 256, 0, stream>>>(cnt, NP);
    count_dst_k<<<(E+255)/256, 256, 0, stream>>>(d, E, cnt);
    scan_excl_k<<<1, 1024, 0, stream>>>(cnt, ofs, cursor, NP);
    scatter_k<<<(E+255)/256, 256, 0, stream>>>(s, d, E, cursor, colv);
  };
  auto gemm = [&]<int BN, typename OutT, bool BIAS>(const ushort* A, const ushort* BT,
      const float* bias, OutT* C, int M, int N, int K, int lda, int ldc){
    int Npad = (N + BN - 1)/BN*BN;
    dim3 g((M + 127)/128, Npad/BN);
    gemm_mfma<BN, OutT, BIAS><<<g, 256, 0, stream>>>(A, BT, bias, C, M, N, K, lda, ldc);
  };

  // ----- CSR + conversions -----
  build(meta_src, meta_dst, EM, ofsm, colm);
  build(q_src, q_dst, EQ, ofsq, colq);
  build(k_src, k_dst, EK, ofsk, colk);
  build(a_src, a_dst, EA, ofsa, cola);
  cvt(hp, hp_b, (size_t)NP*128);
  cvt(hq, fq_b, (size_t)NQ*64);
  cvt(hk, fk_b, (size_t)NK*64);
  cvt(ha, fa_b, (size_t)NA*64);
  wT(W0, W0T, 128, 128, 128);      wT(W1, W1T, 128, 128, 128);
  wT(Wq, WqT, 64, 512, 512);       wT(Wkw, WkwT, 64, 512, 512);
  wT(Watt, WattT, 64, 512, 512);   wT(Wpn, WpnT, 512, 64, 64);
  wT(Wpnn, WpnnT, 128, 64, 64);    wT(Wpnn_a, Wpnn_aT, 128, 64, 64);
  wT(Wpn_a, Wpn_aT, 64, 64, 64);   wT(Wpred, WpredT, 256, 1000, 1024);

  // ----- metapath GAT layer 0 -----
  gemm.template operator()<128, ushort, false>(hp_b, W0T, nullptr, hs_b, NP, 128, 128, 128, 128);
  fold_k<<<2, 256, 0, stream>>>(W0, al0, wfa, 128, 32);
  fold_k<<<2, 256, 0, stream>>>(W0, ar0, wfb, 128, 32);
  gemv8_t<float><<<(NP+3)/4, 256, 0, stream>>>(hp, wfa, wfb, el, er, NP, 128, 128);
  gat_agg2<32><<<(NP+3)/4, 256, 0, stream>>>(hs_b, el, er, ofsm, colm, b0, hbuf_b, NP);

  // ----- metapath GAT layer 1 -----
  gemm.template operator()<128, ushort, false>(hbuf_b, W1T, nullptr, hs_b, NP, 128, 128, 128, 128);
  fold_k<<<2, 256, 0, stream>>>(W1, al1, wfa, 128, 32);
  fold_k<<<2, 256, 0, stream>>>(W1, ar1, wfb, 128, 32);
  gemv8_t<ushort><<<(NP+3)/4, 256, 0, stream>>>(hbuf_b, wfa, wfb, el, er, NP, 128, 128);
  gat_agg2<32><<<(NP+3)/4, 256, 0, stream>>>(hs_b, el, er, ofsm, colm, b1, hbuf_b, NP);

  // ----- hcat[:,0:64] = h @ Wpnn ; hpd = hp @ Wpnn_a -----
  gemm.template operator()<64, ushort, false>(hbuf_b, WpnnT, nullptr, hcat_b, NP, 64, 128, 128, 256);
  gemm.template operator()<64, ushort, false>(hp_b, Wpnn_aT, nullptr, hpd_b, NP, 64, 128, 128, 64);

  // ----- bipartite GATs -----
  auto bip = [&](const ushort* feat_b, int Ns, const int* ofs, const int* colv,
                 const float* W, const ushort* WT_, const float* alp, const float* arp,
                 const float* bb, int colofs){
    gemm.template operator()<64, ushort, false>(feat_b, Wpn_aT, nullptr, proj_b, Ns, 64, 64, 64, 64);
    gemm.template operator()<128, ushort, false>(proj_b, WT_, nullptr, hs_b, Ns, 512, 64, 64, 512);
    fold_k<<<1, 256, 0, stream>>>(W, alp, wfa, 64, 128);
    fold_k<<<1, 256, 0, stream>>>(W, arp, wfb, 64, 128);
    gemv4_t<ushort><<<(Ns+3)/4, 256, 0, stream>>>(proj_b, wfa, el, Ns, 64, 64);
    gemv4_t<ushort><<<(NP+3)/4, 256, 0, stream>>>(hpd_b, wfb, er, NP, 64, 64);
    gat_agg2<128><<<(NP+3)/4, 256, 0, stream>>>(hs_b, el, er, ofs, colv, bb, o_b, NP);
    gemm.template operator()<64, ushort, false>(o_b, WpnT, nullptr, hcat_b + colofs, NP, 64, 512, 512, 256);
  };
  bip(fq_b, NQ, ofsq, colq, Wq,  WqT,  alq,  arq,  bq,  64);
  bip(fk_b, NK, ofsk, colk, Wkw, WkwT, alkw, arkw, bkw, 128);
  bip(fa_b, NA, ofsa, cola, Watt,WattT,alatt,aratt,batt,192);

  // ----- final: out = hcat @ Wpred + bpred -----
  gemm.template operator()<128, float, true>(hcat_b, WpredT, bpred, (float*)d_out, NP, 1000, 256, 256, 1000);
}